// Round 1
// baseline (409.341 us; speedup 1.0000x reference)
//
#include <hip/hip_runtime.h>
#include <stdint.h>

#define NIMG 32
#define HGT 384
#define WID 384
#define HW (HGT*WID)          // 147456
#define TOPK 1000
#define KPAD 1024
#define NBINS 4096
#define CANDCAP 2048
#define THRESH 0.05f
#define NMS_T 0.4f

// workspace layout (bytes)
#define HIST_BYTES (NIMG*NBINS*4)      // 524288
#define CNT_OFF HIST_BYTES             // 32 * u32
#define TBIN_OFF (CNT_OFF + 128)       // 32 * i32
#define CAND_OFF (TBIN_OFF + 128)      // 32 * 2048 * u64
#define ZERO_BYTES (TBIN_OFF + 128)    // hist + cnt (+tbin, harmless)

typedef unsigned long long u64;
typedef unsigned int u32;

// ---------- numerics helpers (fp-contraction-proof, matches numpy f32) ----------
__device__ __forceinline__ float area_of(float x0, float y0, float x1, float y1) {
  float a = fmaxf(x1 - x0, 0.0f) * fmaxf(y1 - y0, 0.0f);
  asm volatile("" : "+v"(a));   // block fma fusion into later add/sub
  return a;
}

__device__ __forceinline__ bool iou_gt(float ax0, float ay0, float ax1, float ay1, float aa,
                                       float bx0, float by0, float bx1, float by1, float ba) {
  float ix1 = fmaxf(ax0, bx0);
  float iy1 = fmaxf(ay0, by0);
  float ix2 = fminf(ax1, bx1);
  float iy2 = fminf(ay1, by1);
  float iw = fmaxf(ix2 - ix1, 0.0f);
  float ih = fmaxf(iy2 - iy1, 0.0f);
  float inter = iw * ih;
  asm volatile("" : "+v"(inter));
  float uni = fmaxf(aa + ba - inter, 1e-9f);
  return (inter / uni) > NMS_T;   // IEEE f32 divide (no fast-math)
}

__device__ __forceinline__ u64 shfl64(u64 v, int lane) {
  int lo = __shfl((int)(u32)v, lane, 64);
  int hi = __shfl((int)(u32)(v >> 32), lane, 64);
  return ((u64)(u32)hi << 32) | (u32)lo;
}

// ---------- kernel A: per-image histogram of score bins ----------
__global__ void hist_kernel(const float* __restrict__ cls, u32* __restrict__ hist) {
  __shared__ u32 h[NBINS];
  const int n = blockIdx.y;
  for (int i = threadIdx.x; i < NBINS; i += 256) h[i] = 0;
  __syncthreads();
  const float4* src = (const float4*)(cls + (size_t)n * HW);
  const int base = blockIdx.x * 2048;
  for (int v = 0; v < 8; v++) {
    float4 s4 = src[base + v * 256 + threadIdx.x];
    float ss[4] = {s4.x, s4.y, s4.z, s4.w};
#pragma unroll
    for (int c = 0; c < 4; c++) {
      float s = ss[c];
      if (s > THRESH) {
        int b = (int)(s * 4096.0f);
        b = b < 0 ? 0 : (b > NBINS - 1 ? NBINS - 1 : b);
        atomicAdd(&h[b], 1u);
      }
    }
  }
  __syncthreads();
  u32* gh = hist + n * NBINS;
  for (int i = threadIdx.x; i < NBINS; i += 256)
    if (h[i]) atomicAdd(&gh[i], h[i]);
}

// ---------- kernel B: find threshold bin (largest t with suffix >= TOPK) ----------
__global__ void thresh_kernel(const u32* __restrict__ hist, int* __restrict__ tbin) {
  __shared__ u32 csum[256];
  const int n = blockIdx.x;
  const u32* h = hist + n * NBINS;
  u32 s = 0;
  for (int b = 0; b < 16; b++) s += h[threadIdx.x * 16 + b];
  csum[threadIdx.x] = s;
  __syncthreads();
  if (threadIdx.x == 0) {
    u32 acc = 0;
    int t = 0;
    for (int c = 255; c >= 0; c--) {
      if (acc + csum[c] >= TOPK) {
        for (int b = c * 16 + 15; b >= c * 16; b--) {
          acc += h[b];
          if (acc >= TOPK) { t = b; break; }
        }
        tbin[n] = t;
        return;
      }
      acc += csum[c];
    }
    tbin[n] = 0;  // fewer than TOPK above score threshold
  }
}

// ---------- kernel C: collect candidate keys (score bin >= t) ----------
__global__ void collect_kernel(const float* __restrict__ cls, const int* __restrict__ tbin,
                               u32* __restrict__ cnt, u64* __restrict__ cand) {
  const int n = blockIdx.y;
  const int t = tbin[n];
  const float4* src = (const float4*)(cls + (size_t)n * HW);
  const int base = blockIdx.x * 2048;
  for (int v = 0; v < 8; v++) {
    int p4 = base + v * 256 + threadIdx.x;
    float4 s4 = src[p4];
    float ss[4] = {s4.x, s4.y, s4.z, s4.w};
#pragma unroll
    for (int c = 0; c < 4; c++) {
      float s = ss[c];
      if (s > THRESH) {
        int b = (int)(s * 4096.0f);
        b = b < 0 ? 0 : (b > NBINS - 1 ? NBINS - 1 : b);
        if (b >= t) {
          u32 u = __float_as_uint(s);
          u32 ord = (u & 0x80000000u) ? ~u : (u | 0x80000000u);  // order-preserving map
          u32 idx = (u32)(p4 * 4 + c);
          u64 key = ((u64)ord << 32) | (u32)(~idx);  // desc value, asc index
          u32 pos = atomicAdd(&cnt[n], 1u);
          if (pos < CANDCAP) cand[(size_t)n * CANDCAP + pos] = key;
        }
      }
    }
  }
}

// ---------- kernel D: per-image sort + gather + decode + greedy NMS + output ----------
__global__ __launch_bounds__(1024) void nms_kernel(const float* __restrict__ reg,
                                                   const u32* __restrict__ cnt,
                                                   const u64* __restrict__ cand,
                                                   float* __restrict__ out) {
  __shared__ u64 skey[CANDCAP];
  __shared__ float bxs[KPAD][4];
  __shared__ float sc[KPAD];
  __shared__ u64 intra[64];
  __shared__ u64 validw[16], removedw[16], keepw[16];
  __shared__ u64 aliveB;

  const int n = blockIdx.x;
  const int tid = threadIdx.x;
  u32 cn = cnt[n];
  if (cn > CANDCAP) cn = CANDCAP;

  for (int i = tid; i < CANDCAP; i += 1024)
    skey[i] = (i < (int)cn) ? cand[(size_t)n * CANDCAP + i] : 0ull;
  if (tid < 16) { validw[tid] = 0; removedw[tid] = 0; keepw[tid] = 0; }
  __syncthreads();

  // bitonic sort, descending (reproduces lax.top_k order exactly)
  for (int k = 2; k <= CANDCAP; k <<= 1) {
    for (int j = k >> 1; j > 0; j >>= 1) {
      for (int i = tid; i < CANDCAP; i += 1024) {
        int ixj = i ^ j;
        if (ixj > i) {
          u64 a = skey[i], b = skey[ixj];
          bool desc = (i & k) == 0;
          if (desc ? (a < b) : (a > b)) { skey[i] = b; skey[ixj] = a; }
        }
      }
      __syncthreads();
    }
  }

  // gather + decode boxes for top-1000
  {
    int k = tid;
    float x0 = 0.f, y0 = 0.f, x1 = 0.f, y1 = 0.f, s = 0.f;
    bool val = false;
    if (k < TOPK && k < (int)cn) {
      u64 key = skey[k];
      u32 idx = ~(u32)(key & 0xFFFFFFFFull);
      u32 ord = (u32)(key >> 32);
      u32 u = (ord & 0x80000000u) ? (ord & 0x7FFFFFFFu) : ~ord;
      s = __uint_as_float(u);
      int iy = (int)idx / WID;
      int ix = (int)idx - iy * WID;
      float xx = (float)ix * 4.0f;
      float yy = (float)iy * 4.0f;
      const float* rb = reg + (size_t)n * 4 * HW;
      float r0 = rb[idx];
      float r1 = rb[HW + idx];
      float r2 = rb[2 * HW + idx];
      float r3 = rb[3 * HW + idx];
      y0 = yy - r0;  // ymin
      x1 = xx + r1;  // xmax
      y1 = yy + r2;  // ymax
      x0 = xx - r3;  // xmin
      float wsz = x1 - x0, hsz = y1 - y0;
      val = (s > THRESH) && (wsz >= 0.0f) && (hsz >= 0.0f);
    }
    bxs[k][0] = x0; bxs[k][1] = y0; bxs[k][2] = x1; bxs[k][3] = y1; sc[k] = s;
    if (val) atomicOr(&validw[k >> 6], 1ull << (k & 63));
  }
  __syncthreads();

  // greedy NMS: chunked scan, 16 chunks of 64 boxes
  const int w = tid >> 6, lane = tid & 63;
  for (int c = 0; c < 16; c++) {
    const int cb = c << 6;
    // 1) intra-chunk 64x64 suppression rows via ballot: wave w computes rows w*4..w*4+3
    float mx0 = bxs[cb + lane][0], my0 = bxs[cb + lane][1];
    float mx1 = bxs[cb + lane][2], my1 = bxs[cb + lane][3];
    float marea = area_of(mx0, my0, mx1, my1);
#pragma unroll
    for (int q = 0; q < 4; q++) {
      int l = (w << 2) | q;
      float lx0 = bxs[cb + l][0], ly0 = bxs[cb + l][1];
      float lx1 = bxs[cb + l][2], ly1 = bxs[cb + l][3];
      float larea = area_of(lx0, ly0, lx1, ly1);
      bool pred = iou_gt(lx0, ly0, lx1, ly1, larea, mx0, my0, mx1, my1, marea);
      u64 row = __ballot(pred);
      if (lane == 0) intra[l] = row;
    }
    __syncthreads();
    // 2) wave 0 resolves intra-chunk keep set (ffs skip loop; iterations = #kept)
    if (tid < 64) {
      u64 myrow = intra[lane];
      u64 alive = validw[c] & ~removedw[c];
      u64 cur = alive;
      while (cur) {
        int i = __ffsll(cur) - 1;           // lowest surviving index => kept
        u64 row = shfl64(myrow, i);
        u64 lowmask = (i == 63) ? ~0ull : ((1ull << (i + 1)) - 1ull);
        row &= ~lowmask;                     // suppress only j > i
        alive &= ~row;
        cur &= ~row;
        cur &= cur - 1;                      // pop bit i
      }
      if (lane == 0) { keepw[c] = alive; aliveB = alive; }
    }
    __syncthreads();
    // 3) cross-chunk: kept boxes of chunk c suppress all later boxes
    u64 am = aliveB;
    bool suppr = false;
    int j = ((c + 1) << 6) + tid;
    if (am && j < KPAD) {
      float jx0 = bxs[j][0], jy0 = bxs[j][1], jx1 = bxs[j][2], jy1 = bxs[j][3];
      float jarea = area_of(jx0, jy0, jx1, jy1);
      u64 m = am;
      while (m) {
        int i = __ffsll(m) - 1;
        m &= m - 1;
        int bi = cb + i;
        float px0 = bxs[bi][0], py0 = bxs[bi][1], px1 = bxs[bi][2], py1 = bxs[bi][3];
        float parea = area_of(px0, py0, px1, py1);
        suppr |= iou_gt(px0, py0, px1, py1, parea, jx0, jy0, jx1, jy1, jarea);
      }
    }
    u64 mask = __ballot(suppr);
    int word = c + 1 + w;
    if (lane == 0 && word < 16 && mask) atomicOr(&removedw[word], mask);
    __syncthreads();
  }

  // output: out[n][k][5] = (box, score) * keep ; keep as float
  if (tid < TOPK) {
    u64 kb = (keepw[tid >> 6] >> (tid & 63)) & 1ull;
    float f = (float)kb;
    size_t ob = (size_t)n * (TOPK * 5) + (size_t)tid * 5;
    out[ob + 0] = kb ? bxs[tid][0] : 0.0f;
    out[ob + 1] = kb ? bxs[tid][1] : 0.0f;
    out[ob + 2] = kb ? bxs[tid][2] : 0.0f;
    out[ob + 3] = kb ? bxs[tid][3] : 0.0f;
    out[ob + 4] = kb ? sc[tid] : 0.0f;
    out[(size_t)NIMG * TOPK * 5 + (size_t)n * TOPK + tid] = f;
  }
}

extern "C" void kernel_launch(void* const* d_in, const int* in_sizes, int n_in,
                              void* d_out, int out_size, void* d_ws, size_t ws_size,
                              hipStream_t stream) {
  const float* cls = (const float*)d_in[0];   // (32,1,384,384) f32
  const float* reg = (const float*)d_in[1];   // (32,4,384,384) f32
  // d_in[2] image_sizes unused by reference _forward
  float* out = (float*)d_out;                 // 160000 (out) + 32000 (keep) f32

  uint8_t* ws = (uint8_t*)d_ws;
  u32* hist = (u32*)(ws);
  u32* cnt = (u32*)(ws + CNT_OFF);
  int* tbin = (int*)(ws + TBIN_OFF);
  u64* cand = (u64*)(ws + CAND_OFF);

  hipMemsetAsync(ws, 0, ZERO_BYTES, stream);  // zero hist + cnt
  hist_kernel<<<dim3(18, NIMG), 256, 0, stream>>>(cls, hist);
  thresh_kernel<<<NIMG, 256, 0, stream>>>(hist, tbin);
  collect_kernel<<<dim3(18, NIMG), 256, 0, stream>>>(cls, tbin, cnt, cand);
  nms_kernel<<<NIMG, 1024, 0, stream>>>(reg, cnt, cand, out);
}

// Round 2
// 256.890 us; speedup vs baseline: 1.5934x; 1.5934x over previous
//
#include <hip/hip_runtime.h>
#include <stdint.h>

#define NIMG 32
#define WID 384
#define HW 147456            // 384*384
#define TOPK 1000
#define KPAD 1024
#define NBINS 512
#define BIN_SCALEF 512.0f
#define PRECAP 8192
#define LBUF 1024
#define CANDCAP 2048
#define THRESH 0.05f
#define PREF_C 0.97f
#define NMS_T 0.4f
#define NBLK 18              // scan blocks per image (18*2048 float4 = 147456 floats)

typedef unsigned long long u64;
typedef unsigned int u32;

// ---------------- workspace layout (bytes) ----------------
// 0      : cnt[32]  u32   (zeroed each launch)
// 128    : flag[32] u32   (zeroed each launch)
// 256    : tbin[32] i32   (always written by thresh_kernel)
// 512    : phist[NIMG*NBLK*NBINS] u32 = 1,179,648  (fully overwritten)
// 1180160: precand[NIMG*PRECAP] u64   = 2,097,152  (read only up to cnt)
#define FLAG_OFF 128
#define TBIN_OFF 256
#define PHIST_OFF 512
#define PRECAND_OFF (PHIST_OFF + NIMG*NBLK*NBINS*4)
#define ZERO_BYTES 256

// ---------- numerics helpers (fp-contraction-proof, matches numpy f32) ----------
__device__ __forceinline__ float area_of(float x0, float y0, float x1, float y1) {
  float a = fmaxf(x1 - x0, 0.0f) * fmaxf(y1 - y0, 0.0f);
  asm volatile("" : "+v"(a));   // block fma fusion into later add/sub
  return a;
}

__device__ __forceinline__ bool iou_gt(float ax0, float ay0, float ax1, float ay1, float aa,
                                       float bx0, float by0, float bx1, float by1, float ba) {
  float ix1 = fmaxf(ax0, bx0);
  float iy1 = fmaxf(ay0, by0);
  float ix2 = fminf(ax1, bx1);
  float iy2 = fminf(ay1, by1);
  float iw = fmaxf(ix2 - ix1, 0.0f);
  float ih = fmaxf(iy2 - iy1, 0.0f);
  float inter = iw * ih;
  asm volatile("" : "+v"(inter));
  float uni = fmaxf(aa + ba - inter, 1e-9f);
  return (inter / uni) > NMS_T;   // IEEE f32 divide (no fast-math)
}

__device__ __forceinline__ u64 shfl64(u64 v, int lane) {
  int lo = __shfl((int)(u32)v, lane, 64);
  int hi = __shfl((int)(u32)(v >> 32), lane, 64);
  return ((u64)(u32)hi << 32) | (u32)lo;
}

// key: (ord << 32) | ~idx ; ord = bits(s)|signbit (s always > 0 here)
// sorts desc by score, ties -> ascending index (matches lax.top_k)
__device__ __forceinline__ u64 make_key(float s, u32 idx) {
  u32 ord = __float_as_uint(s) | 0x80000000u;
  return ((u64)ord << 32) | (u32)(~idx);
}

// ---------- kernel 1: fused scan — per-block private hist + prefilter collect ----------
__global__ void scan_kernel(const float* __restrict__ cls, u32* __restrict__ phist,
                            u32* __restrict__ cnt, u32* __restrict__ flag,
                            u64* __restrict__ precand) {
  __shared__ u32 h[NBINS];
  __shared__ u64 lbuf[LBUF];
  __shared__ u32 lcnt, gbase, wcnt;
  const int n = blockIdx.y;
  const int tid = threadIdx.x;
  const int lane = tid & 63;
  for (int i = tid; i < NBINS; i += 256) h[i] = 0;
  if (tid == 0) lcnt = 0;
  __syncthreads();

  const float4* src = (const float4*)(cls + (size_t)n * HW);
  const int p0 = blockIdx.x * 2048 + tid;
  const u64 ltmask = (1ull << lane) - 1ull;
  for (int v = 0; v < 8; v += 2) {
    float4 a = src[p0 + v * 256];        // two independent loads in flight
    float4 b4 = src[p0 + (v + 1) * 256];
    float ss[8] = {a.x, a.y, a.z, a.w, b4.x, b4.y, b4.z, b4.w};
#pragma unroll
    for (int c = 0; c < 8; c++) {
      float s = ss[c];
      if (s > THRESH) {
        int b = (int)(s * BIN_SCALEF);
        b = b < 0 ? 0 : (b > NBINS - 1 ? NBINS - 1 : b);
        atomicAdd(&h[b], 1u);            // LDS atomic only
      }
      bool pc = s > PREF_C;
      u64 m = __ballot(pc);
      if (m) {
        int ldr = __ffsll((unsigned long long)m) - 1;
        u32 wb = 0;
        if (lane == ldr) wb = atomicAdd(&lcnt, (u32)__popcll(m));  // LDS atomic, 1/wave-step
        wb = (u32)__shfl((int)wb, ldr, 64);
        if (pc) {
          u32 pos = wb + (u32)__popcll(m & ltmask);
          if (pos < LBUF) {
            int p4 = p0 + ((c < 4) ? v : (v + 1)) * 256;
            lbuf[pos] = make_key(s, (u32)(p4 * 4 + (c & 3)));
          }
        }
      }
    }
  }
  __syncthreads();
  // flush private histogram (plain coalesced stores — no global atomics)
  u32* ph = phist + ((size_t)n * NBLK + blockIdx.x) * NBINS;
  for (int i = tid; i < NBINS; i += 256) ph[i] = h[i];
  // ONE global fetch-add per block to reserve output range
  if (tid == 0) {
    u32 c = lcnt < LBUF ? lcnt : (u32)LBUF;
    if (lcnt > LBUF) atomicOr(&flag[n], 1u);
    u32 g = atomicAdd(&cnt[n], c);
    if (g + c > PRECAP) atomicOr(&flag[n], 1u);
    gbase = g; wcnt = c;
  }
  __syncthreads();
  u32 c = wcnt, g = gbase;
  u64* pcand = precand + (size_t)n * PRECAP;
  for (u32 i = tid; i < c; i += 256) {
    u32 w = g + i;
    if (w < PRECAP) pcand[w] = lbuf[i];
  }
}

// ---------- kernel 2: reduce partial hists, exact threshold bin, fallback flag ----------
__global__ void thresh_kernel(const u32* __restrict__ phist, u32* __restrict__ cnt,
                              u32* __restrict__ flag, int* __restrict__ tbin) {
  __shared__ u32 bs[NBINS];
  __shared__ u32 tt[256];
  __shared__ int best;
  const int n = blockIdx.x;
  const int tid = threadIdx.x;
  const u32* ph = phist + (size_t)n * NBLK * NBINS;
  u32 s0 = 0, s1 = 0;
#pragma unroll
  for (int p = 0; p < NBLK; p++) {
    s0 += ph[p * NBINS + tid];
    s1 += ph[p * NBINS + tid + 256];
  }
  bs[tid] = s0; bs[tid + 256] = s1;
  if (tid == 0) best = 0;
  __syncthreads();
  // inclusive suffix-sum over 256 per-thread (2-bin) totals
  tt[tid] = bs[tid * 2] + bs[tid * 2 + 1];
  __syncthreads();
  for (int ofs = 1; ofs < 256; ofs <<= 1) {
    u32 v = (tid + ofs < 256) ? tt[tid + ofs] : 0;
    __syncthreads();
    tt[tid] += v;
    __syncthreads();
  }
  u32 hi = (tid < 255) ? tt[tid + 1] : 0;
  u32 suf1 = hi + bs[tid * 2 + 1];
  u32 suf0 = suf1 + bs[tid * 2];
  int tl = -1;
  if (suf1 >= TOPK) tl = tid * 2 + 1;
  else if (suf0 >= TOPK) tl = tid * 2;
  if (tl > 0) atomicMax(&best, tl);
  __syncthreads();
  if (tid == 0) {
    tbin[n] = best;
    u32 cn = cnt[n];
    if (flag[n] != 0 || cn < TOPK) { flag[n] = 1u; cnt[n] = 0u; }  // prefilter unusable
  }
}

// ---------- kernel 3: exact fallback collect (dead path normally; early-exits) ----------
__global__ void fallback_kernel(const float* __restrict__ cls, const u32* __restrict__ flag,
                                const int* __restrict__ tbin, u32* __restrict__ cnt,
                                u64* __restrict__ precand) {
  const int n = blockIdx.y;
  if (flag[n] == 0u) return;
  __shared__ u64 lbuf[LBUF];
  __shared__ u32 lcnt, gbase, wcnt;
  const int tid = threadIdx.x;
  const int lane = tid & 63;
  if (tid == 0) lcnt = 0;
  __syncthreads();
  const int t = tbin[n];
  const float4* src = (const float4*)(cls + (size_t)n * HW);
  const int p0 = blockIdx.x * 2048 + tid;
  const u64 ltmask = (1ull << lane) - 1ull;
  for (int v = 0; v < 8; v += 2) {
    float4 a = src[p0 + v * 256];
    float4 b4 = src[p0 + (v + 1) * 256];
    float ss[8] = {a.x, a.y, a.z, a.w, b4.x, b4.y, b4.z, b4.w};
#pragma unroll
    for (int c = 0; c < 8; c++) {
      float s = ss[c];
      bool p = false;
      if (s > THRESH) {
        int b = (int)(s * BIN_SCALEF);
        b = b < 0 ? 0 : (b > NBINS - 1 ? NBINS - 1 : b);
        p = (b >= t);
      }
      u64 m = __ballot(p);
      if (m) {
        int ldr = __ffsll((unsigned long long)m) - 1;
        u32 wb = 0;
        if (lane == ldr) wb = atomicAdd(&lcnt, (u32)__popcll(m));
        wb = (u32)__shfl((int)wb, ldr, 64);
        if (p) {
          u32 pos = wb + (u32)__popcll(m & ltmask);
          if (pos < LBUF) {
            int p4 = p0 + ((c < 4) ? v : (v + 1)) * 256;
            lbuf[pos] = make_key(s, (u32)(p4 * 4 + (c & 3)));
          }
        }
      }
    }
  }
  __syncthreads();
  if (tid == 0) {
    u32 c = lcnt < LBUF ? lcnt : (u32)LBUF;
    u32 g = atomicAdd(&cnt[n], c);
    gbase = g; wcnt = c;
  }
  __syncthreads();
  u32 c = wcnt, g = gbase;
  u64* pcand = precand + (size_t)n * PRECAP;
  for (u32 i = tid; i < c; i += 256) {
    u32 w = g + i;
    if (w < PRECAP) pcand[w] = lbuf[i];
  }
}

// ---------- kernel 4: filter + sort + gather/decode + greedy NMS + output ----------
__global__ __launch_bounds__(1024) void nms_kernel(const float* __restrict__ reg,
                                                   const u32* __restrict__ cnt,
                                                   const int* __restrict__ tbin,
                                                   const u64* __restrict__ precand,
                                                   float* __restrict__ out) {
  __shared__ u64 skey[CANDCAP];
  __shared__ float bxs[KPAD][4];
  __shared__ float sc[KPAD];
  __shared__ u32 sfc;
  __shared__ u64 intra[64];
  __shared__ u64 validw[16], removedw[16], keepw[16];
  __shared__ u64 aliveB;

  const int n = blockIdx.x;
  const int tid = threadIdx.x;
  const int lane = tid & 63;
  u32 cn = cnt[n];
  if (cn > PRECAP) cn = PRECAP;
  const int t = tbin[n];

  skey[tid] = 0ull; skey[tid + 1024] = 0ull;
  if (tid == 0) sfc = 0;
  if (tid < 16) { validw[tid] = 0; removedw[tid] = 0; keepw[tid] = 0; }
  __syncthreads();

  // filter prefiltered keys by exact threshold bin (ballot-compacted)
  const u64* pcand = precand + (size_t)n * PRECAP;
  const u64 ltmask = (1ull << lane) - 1ull;
  for (u32 base = 0; base < cn; base += 1024) {
    u32 i = base + tid;
    bool p = false; u64 key = 0;
    if (i < cn) {
      key = pcand[i];
      float s = __uint_as_float((u32)(key >> 32) & 0x7FFFFFFFu);
      if (s > THRESH) {
        int b = (int)(s * BIN_SCALEF);
        b = b < 0 ? 0 : (b > NBINS - 1 ? NBINS - 1 : b);
        p = (b >= t);
      }
    }
    u64 m = __ballot(p);
    if (m) {
      int ldr = __ffsll((unsigned long long)m) - 1;
      u32 wb = 0;
      if (lane == ldr) wb = atomicAdd(&sfc, (u32)__popcll(m));
      wb = (u32)__shfl((int)wb, ldr, 64);
      if (p) {
        u32 pos = wb + (u32)__popcll(m & ltmask);
        if (pos < CANDCAP) skey[pos] = key;
      }
    }
  }
  __syncthreads();
  u32 fc = sfc; if (fc > CANDCAP) fc = CANDCAP;

  // bitonic sort 2048, descending (reproduces lax.top_k order exactly)
  for (int k = 2; k <= CANDCAP; k <<= 1) {
    for (int j = k >> 1; j > 0; j >>= 1) {
      for (int i = tid; i < CANDCAP; i += 1024) {
        int ixj = i ^ j;
        if (ixj > i) {
          u64 a = skey[i], b = skey[ixj];
          bool desc = (i & k) == 0;
          if (desc ? (a < b) : (a > b)) { skey[i] = b; skey[ixj] = a; }
        }
      }
      __syncthreads();
    }
  }

  // gather + decode boxes for top-1000
  {
    int k = tid;
    float x0 = 0.f, y0 = 0.f, x1 = 0.f, y1 = 0.f, s = 0.f;
    bool val = false;
    if (k < TOPK && k < (int)fc) {
      u64 key = skey[k];
      u32 idx = ~(u32)(key & 0xFFFFFFFFull);
      s = __uint_as_float((u32)(key >> 32) & 0x7FFFFFFFu);
      int iy = (int)idx / WID;
      int ix = (int)idx - iy * WID;
      float xx = (float)ix * 4.0f;
      float yy = (float)iy * 4.0f;
      const float* rb = reg + (size_t)n * 4 * HW;
      float r0 = rb[idx];
      float r1 = rb[HW + idx];
      float r2 = rb[2 * HW + idx];
      float r3 = rb[3 * HW + idx];
      y0 = yy - r0;  // ymin
      x1 = xx + r1;  // xmax
      y1 = yy + r2;  // ymax
      x0 = xx - r3;  // xmin
      float wsz = x1 - x0, hsz = y1 - y0;
      val = (s > THRESH) && (wsz >= 0.0f) && (hsz >= 0.0f);
    }
    bxs[k][0] = x0; bxs[k][1] = y0; bxs[k][2] = x1; bxs[k][3] = y1; sc[k] = s;
    if (val) atomicOr(&validw[k >> 6], 1ull << (k & 63));
  }
  __syncthreads();

  // greedy NMS: chunked scan, 16 chunks of 64 boxes
  const int w = tid >> 6;
  for (int c = 0; c < 16; c++) {
    const int cb = c << 6;
    float mx0 = bxs[cb + lane][0], my0 = bxs[cb + lane][1];
    float mx1 = bxs[cb + lane][2], my1 = bxs[cb + lane][3];
    float marea = area_of(mx0, my0, mx1, my1);
#pragma unroll
    for (int q = 0; q < 4; q++) {
      int l = (w << 2) | q;
      float lx0 = bxs[cb + l][0], ly0 = bxs[cb + l][1];
      float lx1 = bxs[cb + l][2], ly1 = bxs[cb + l][3];
      float larea = area_of(lx0, ly0, lx1, ly1);
      bool pred = iou_gt(lx0, ly0, lx1, ly1, larea, mx0, my0, mx1, my1, marea);
      u64 row = __ballot(pred);
      if (lane == 0) intra[l] = row;
    }
    __syncthreads();
    if (tid < 64) {
      u64 myrow = intra[lane];
      u64 alive = validw[c] & ~removedw[c];
      u64 cur = alive;
      while (cur) {
        int i = __ffsll(cur) - 1;
        u64 row = shfl64(myrow, i);
        u64 lowmask = (i == 63) ? ~0ull : ((1ull << (i + 1)) - 1ull);
        row &= ~lowmask;
        alive &= ~row;
        cur &= ~row;
        cur &= cur - 1;
      }
      if (lane == 0) { keepw[c] = alive; aliveB = alive; }
    }
    __syncthreads();
    u64 am = aliveB;
    bool suppr = false;
    int j = ((c + 1) << 6) + tid;
    if (am && j < KPAD) {
      float jx0 = bxs[j][0], jy0 = bxs[j][1], jx1 = bxs[j][2], jy1 = bxs[j][3];
      float jarea = area_of(jx0, jy0, jx1, jy1);
      u64 m = am;
      while (m) {
        int i = __ffsll(m) - 1;
        m &= m - 1;
        int bi = cb + i;
        float px0 = bxs[bi][0], py0 = bxs[bi][1], px1 = bxs[bi][2], py1 = bxs[bi][3];
        float parea = area_of(px0, py0, px1, py1);
        suppr |= iou_gt(px0, py0, px1, py1, parea, jx0, jy0, jx1, jy1, jarea);
      }
    }
    u64 mask = __ballot(suppr);
    int word = c + 1 + w;
    if (lane == 0 && word < 16 && mask) atomicOr(&removedw[word], mask);
    __syncthreads();
  }

  // output
  if (tid < TOPK) {
    u64 kb = (keepw[tid >> 6] >> (tid & 63)) & 1ull;
    float f = (float)kb;
    size_t ob = (size_t)n * (TOPK * 5) + (size_t)tid * 5;
    out[ob + 0] = kb ? bxs[tid][0] : 0.0f;
    out[ob + 1] = kb ? bxs[tid][1] : 0.0f;
    out[ob + 2] = kb ? bxs[tid][2] : 0.0f;
    out[ob + 3] = kb ? bxs[tid][3] : 0.0f;
    out[ob + 4] = kb ? sc[tid] : 0.0f;
    out[(size_t)NIMG * TOPK * 5 + (size_t)n * TOPK + tid] = f;
  }
}

extern "C" void kernel_launch(void* const* d_in, const int* in_sizes, int n_in,
                              void* d_out, int out_size, void* d_ws, size_t ws_size,
                              hipStream_t stream) {
  const float* cls = (const float*)d_in[0];   // (32,1,384,384) f32
  const float* reg = (const float*)d_in[1];   // (32,4,384,384) f32
  float* out = (float*)d_out;                 // 160000 (out) + 32000 (keep) f32

  uint8_t* ws = (uint8_t*)d_ws;
  u32* cnt = (u32*)(ws);
  u32* flag = (u32*)(ws + FLAG_OFF);
  int* tbin = (int*)(ws + TBIN_OFF);
  u32* phist = (u32*)(ws + PHIST_OFF);
  u64* precand = (u64*)(ws + PRECAND_OFF);

  hipMemsetAsync(ws, 0, ZERO_BYTES, stream);  // zero cnt + flag only
  scan_kernel<<<dim3(NBLK, NIMG), 256, 0, stream>>>(cls, phist, cnt, flag, precand);
  thresh_kernel<<<NIMG, 256, 0, stream>>>(phist, cnt, flag, tbin);
  fallback_kernel<<<dim3(NBLK, NIMG), 256, 0, stream>>>(cls, flag, tbin, cnt, precand);
  nms_kernel<<<NIMG, 1024, 0, stream>>>(reg, cnt, tbin, precand, out);
}

// Round 3
// 237.715 us; speedup vs baseline: 1.7220x; 1.0807x over previous
//
#include <hip/hip_runtime.h>
#include <stdint.h>

#define NIMG 32
#define WID 384
#define HW 147456            // 384*384
#define TOPK 1000
#define KPAD 1024
#define NBINS 512
#define BIN_SCALEF 512.0f
#define SEGCAP 512
#define CANDCAP 2048
#define THRESH 0.05f
#define PREF_C 0.97f
#define PREF_BIN_MIN 497     // bin 497 edge = 0.970703 > 0.97f => prefilter superset
#define NMS_T 0.4f
#define NBLK 18              // scan blocks per image (18*2048 float4 = 147456 floats)

typedef unsigned long long u64;
typedef unsigned int u32;

// ---------------- workspace layout (bytes); everything fully overwritten ----------------
#define PCNT_OFF 0                        // NIMG*NBLK u32 = 2304
#define PHIST_OFF 4096                    // NIMG*NBLK*256 u32 (2 u16 bins packed) = 589824
#define PCAND_OFF (PHIST_OFF + NIMG*NBLK*256*4)   // NIMG*NBLK*SEGCAP u64 = 2359296

// ---------- numerics helpers (fp-contraction-proof, matches numpy f32) ----------
__device__ __forceinline__ float area_of(float x0, float y0, float x1, float y1) {
  float a = fmaxf(x1 - x0, 0.0f) * fmaxf(y1 - y0, 0.0f);
  asm volatile("" : "+v"(a));
  return a;
}

__device__ __forceinline__ bool iou_gt(float ax0, float ay0, float ax1, float ay1, float aa,
                                       float bx0, float by0, float bx1, float by1, float ba) {
  float ix1 = fmaxf(ax0, bx0);
  float iy1 = fmaxf(ay0, by0);
  float ix2 = fminf(ax1, bx1);
  float iy2 = fminf(ay1, by1);
  float iw = fmaxf(ix2 - ix1, 0.0f);
  float ih = fmaxf(iy2 - iy1, 0.0f);
  float inter = iw * ih;
  asm volatile("" : "+v"(inter));
  float uni = fmaxf(aa + ba - inter, 1e-9f);
  return (inter / uni) > NMS_T;
}

__device__ __forceinline__ u64 shflxor64(u64 v, int m) {
  int lo = __shfl_xor((int)(u32)v, m, 64);
  int hi = __shfl_xor((int)(u32)(v >> 32), m, 64);
  return ((u64)(u32)hi << 32) | (u32)lo;
}

__device__ __forceinline__ u64 make_key(float s, u32 idx) {
  u32 ord = __float_as_uint(s) | 0x80000000u;   // s > 0 always here
  return ((u64)ord << 32) | (u32)(~idx);        // desc score, ties asc index (lax.top_k)
}

__device__ __forceinline__ int bin_of(float s) {
  int b = (int)(s * BIN_SCALEF);
  return b < 0 ? 0 : (b > NBINS - 1 ? NBINS - 1 : b);
}

// ---------- kernel 1: per-block private hist + prefilter collect (no global atomics) ----------
__global__ void scan_kernel(const float* __restrict__ cls, u32* __restrict__ phist,
                            u32* __restrict__ pcnt, u64* __restrict__ pcand) {
  __shared__ u32 h[NBINS];
  __shared__ u64 lbuf[SEGCAP];
  __shared__ u32 lcnt;
  const int n = blockIdx.y;
  const int tid = threadIdx.x;
  const int lane = tid & 63;
  h[tid] = 0; h[tid + 256] = 0;
  if (tid == 0) lcnt = 0;
  __syncthreads();

  const float4* src = (const float4*)(cls + (size_t)n * HW) + blockIdx.x * 2048;
  float4 A[8];
#pragma unroll
  for (int v = 0; v < 8; v++) A[v] = src[tid + v * 256];   // 8 loads in flight

  const u64 ltmask = (1ull << lane) - 1ull;
#pragma unroll
  for (int v = 0; v < 8; v++) {
    float ss[4] = {A[v].x, A[v].y, A[v].z, A[v].w};
#pragma unroll
    for (int c = 0; c < 4; c++) {
      float s = ss[c];
      if (s > THRESH) atomicAdd(&h[bin_of(s)], 1u);        // LDS atomic only
      bool pc = s > PREF_C;
      u64 m = __ballot(pc);
      if (m) {
        int ldr = __ffsll(m) - 1;
        u32 wb = 0;
        if (lane == ldr) wb = atomicAdd(&lcnt, (u32)__popcll(m));
        wb = (u32)__shfl((int)wb, ldr, 64);
        if (pc) {
          u32 pos = wb + (u32)__popcll(m & ltmask);
          if (pos < SEGCAP) lbuf[pos] = make_key(s, (u32)((blockIdx.x * 2048 + tid + v * 256) * 4 + c));
        }
      }
    }
  }
  __syncthreads();
  const int seg = n * NBLK + blockIdx.x;
  // packed u16 histogram, plain coalesced stores
  phist[seg * 256 + tid] = (h[2 * tid] & 0xFFFFu) | (h[2 * tid + 1] << 16);
  if (tid == 0) pcnt[seg] = (lcnt > SEGCAP) ? 0xFFFFFFFFu : lcnt;
  u32 c = lcnt < SEGCAP ? lcnt : (u32)SEGCAP;
  u64* pc = pcand + (size_t)seg * SEGCAP;
  for (u32 i = tid; i < c; i += 256) pc[i] = lbuf[i];
}

// reg-chain bitonic levels j=jstart..1 for stage k (jstart <= 64, via shuffles, no barriers)
#define REGCHAIN(K, JSTART) do {                                            \
    const bool desc_ = ((tid & ((K) >> 1)) == 0);                           \
    for (int j_ = (JSTART); j_ >= 2; j_ >>= 1) {                            \
      int h_ = j_ >> 1;                                                     \
      bool low_ = (tid & h_) == 0;                                          \
      u64 p0_ = shflxor64(e0, h_), p1_ = shflxor64(e1, h_);                 \
      bool tm_ = (low_ == desc_);                                           \
      e0 = tm_ ? (e0 > p0_ ? e0 : p0_) : (e0 < p0_ ? e0 : p0_);             \
      e1 = tm_ ? (e1 > p1_ ? e1 : p1_) : (e1 < p1_ ? e1 : p1_);             \
    }                                                                       \
    { u64 lo_ = e0 < e1 ? e0 : e1, hi_ = e0 < e1 ? e1 : e0;                 \
      e0 = desc_ ? hi_ : lo_; e1 = desc_ ? lo_ : hi_; }                     \
  } while (0)

// ---------- kernel 2: hist-reduce + threshold + filter + sort + decode + NMS + output ----------
__global__ __launch_bounds__(1024) void mega_kernel(const float* __restrict__ cls,
                                                    const float* __restrict__ reg,
                                                    const u32* __restrict__ phist,
                                                    const u32* __restrict__ pcnt,
                                                    const u64* __restrict__ pcand,
                                                    float* __restrict__ out) {
  __shared__ u64 skey[CANDCAP];        // 16 KB
  __shared__ float bxs[KPAD][4];       // 16 KB
  __shared__ float sc[KPAD];           // 4 KB
  __shared__ u64 intraAll[KPAD];       // 8 KB
  __shared__ u32 bs[NBINS];            // 2 KB
  __shared__ u32 stmp[64];
  __shared__ int stbin;
  __shared__ u32 sflag, sfc;
  __shared__ u64 validw[16], removedw[16], keepw[16];
  __shared__ u64 aliveB;

  const int n = blockIdx.x;
  const int tid = threadIdx.x;
  const int lane = tid & 63;
  const int w = tid >> 6;
  const u64 ltmask = (1ull << lane) - 1ull;

  // ---- stage 1: reduce packed histograms; init state ----
  if (tid < 256) {
    u32 lo = 0, hi = 0;
#pragma unroll
    for (int b = 0; b < NBLK; b++) {
      u32 p = phist[(size_t)(n * NBLK + b) * 256 + tid];
      lo += p & 0xFFFFu; hi += p >> 16;
    }
    bs[2 * tid] = lo; bs[2 * tid + 1] = hi;
  }
  if (tid == 0) {
    u32 f = 0;
    for (int b = 0; b < NBLK; b++) if (pcnt[n * NBLK + b] == 0xFFFFFFFFu) f = 1;
    sflag = f; sfc = 0;
  }
  if (tid < 16) { validw[tid] = 0; removedw[tid] = 0; keepw[tid] = 0; }
  skey[tid] = 0ull; skey[tid + 1024] = 0ull;
  __syncthreads();

  // ---- stage 2: exact threshold bin (wave 0: chunk sums + suffix scan) ----
  if (tid < 64) {
    u32 cs = 0;
#pragma unroll
    for (int k2 = 0; k2 < 8; k2++) cs += bs[lane * 8 + k2];
    u32 s = cs;
#pragma unroll
    for (int d = 1; d < 64; d <<= 1) {
      u32 v = (u32)__shfl_down((int)s, d, 64);
      if (lane + d < 64) s += v;
    }
    stmp[lane] = s;                      // suffix-from-chunk(lane)
    u64 mask = __ballot(s >= TOPK);
    if (lane == 0) {
      int t = 0;
      if (mask) {
        int L = 63 - __clzll(mask);      // largest chunk with suffix >= TOPK
        u32 acc = (L < 63) ? stmp[L + 1] : 0;
        for (int b = L * 8 + 7; b >= L * 8; b--) {
          acc += bs[b];
          if (acc >= TOPK) { t = b; break; }
        }
      }
      stbin = t;
      if (t < PREF_BIN_MIN) sflag = 1;   // prefilter not provably a superset -> exact rescan
    }
  }
  __syncthreads();

  const int t = stbin;
  // ---- stage 3: fill skey with candidates (bin >= t), ballot-compacted ----
  if (sflag == 0) {
    for (int bp = 0; bp < 9; bp++) {
      int seg = bp * 2 + (tid >> 9);
      int i = tid & 511;
      u32 c = pcnt[n * NBLK + seg];
      bool p = false; u64 key = 0;
      if (i < (int)c) {
        key = pcand[(size_t)(n * NBLK + seg) * SEGCAP + i];
        float s = __uint_as_float((u32)(key >> 32) & 0x7FFFFFFFu);
        p = bin_of(s) >= t;
      }
      u64 m = __ballot(p);
      if (m) {
        int ldr = __ffsll(m) - 1;
        u32 wb = 0;
        if (lane == ldr) wb = atomicAdd(&sfc, (u32)__popcll(m));
        wb = (u32)__shfl((int)wb, ldr, 64);
        if (p) { u32 pos = wb + (u32)__popcll(m & ltmask); if (pos < CANDCAP) skey[pos] = key; }
      }
    }
  } else {
    // exact fallback: rescan this image directly (dead path for bench input)
    const float* ci = cls + (size_t)n * HW;
    for (int base = 0; base < HW; base += 1024) {
      int i = base + tid;
      float s = ci[i];
      bool p = (s > THRESH) && (bin_of(s) >= t);
      u64 m = __ballot(p);
      if (m) {
        int ldr = __ffsll(m) - 1;
        u32 wb = 0;
        if (lane == ldr) wb = atomicAdd(&sfc, (u32)__popcll(m));
        wb = (u32)__shfl((int)wb, ldr, 64);
        if (p) { u32 pos = wb + (u32)__popcll(m & ltmask); if (pos < CANDCAP) skey[pos] = make_key(s, (u32)i); }
      }
    }
  }
  __syncthreads();
  u32 fc = sfc; if (fc > CANDCAP) fc = CANDCAP;

  // ---- stage 4: hybrid bitonic sort (2048 keys, 2/thread; shfl for j<=64, LDS for j>=128) ----
  {
    u64 e0 = skey[2 * tid], e1 = skey[2 * tid + 1];
    REGCHAIN(2, 1); REGCHAIN(4, 2); REGCHAIN(8, 4); REGCHAIN(16, 8);
    REGCHAIN(32, 16); REGCHAIN(64, 32); REGCHAIN(128, 64);
    for (int k = 256; k <= CANDCAP; k <<= 1) {
      skey[2 * tid] = e0; skey[2 * tid + 1] = e1;
      __syncthreads();
      for (int j = k >> 1; j >= 128; j >>= 1) {
        int i = ((tid & ~(j - 1)) << 1) | (tid & (j - 1));
        u64 a = skey[i], b = skey[i + j];
        bool desc = ((i & k) == 0);
        if (desc ? (a < b) : (a > b)) { skey[i] = b; skey[i + j] = a; }
        __syncthreads();
      }
      e0 = skey[2 * tid]; e1 = skey[2 * tid + 1];
      REGCHAIN(k, 64);
    }
    skey[2 * tid] = e0; skey[2 * tid + 1] = e1;
    __syncthreads();
  }

  // ---- stage 5: gather + decode top-1000 ----
  {
    float x0 = 0.f, y0 = 0.f, x1 = 0.f, y1 = 0.f, s = 0.f;
    bool val = false;
    if (tid < TOPK && tid < (int)fc) {
      u64 key = skey[tid];
      u32 idx = ~(u32)(key & 0xFFFFFFFFull);
      s = __uint_as_float((u32)(key >> 32) & 0x7FFFFFFFu);
      int iy = (int)idx / WID;
      int ix = (int)idx - iy * WID;
      float xx = (float)ix * 4.0f;
      float yy = (float)iy * 4.0f;
      const float* rb = reg + (size_t)n * 4 * HW;
      float r0 = rb[idx];
      float r1 = rb[HW + idx];
      float r2 = rb[2 * HW + idx];
      float r3 = rb[3 * HW + idx];
      y0 = yy - r0; x1 = xx + r1; y1 = yy + r2; x0 = xx - r3;
      float wsz = x1 - x0, hsz = y1 - y0;
      val = (s > THRESH) && (wsz >= 0.0f) && (hsz >= 0.0f);
    }
    bxs[tid][0] = x0; bxs[tid][1] = y0; bxs[tid][2] = x1; bxs[tid][3] = y1; sc[tid] = s;
    if (val) atomicOr(&validw[tid >> 6], 1ull << (tid & 63));
  }
  __syncthreads();

  // ---- stage 6a: precompute ALL intra-chunk suppression rows (16 waves || 16 chunks) ----
  {
    const int cb = w << 6;
    float mx0 = bxs[cb + lane][0], my0 = bxs[cb + lane][1];
    float mx1 = bxs[cb + lane][2], my1 = bxs[cb + lane][3];
    float marea = area_of(mx0, my0, mx1, my1);
    for (int l = 0; l < 64; l++) {
      float lx0 = bxs[cb + l][0], ly0 = bxs[cb + l][1];   // broadcast reads
      float lx1 = bxs[cb + l][2], ly1 = bxs[cb + l][3];
      float larea = area_of(lx0, ly0, lx1, ly1);
      bool pred = iou_gt(lx0, ly0, lx1, ly1, larea, mx0, my0, mx1, my1, marea);
      u64 row = __ballot(pred);
      if (lane == l) intraAll[cb + l] = row;
    }
  }
  __syncthreads();

  // ---- stage 6b: sequential chunk scan (2 barriers/chunk) ----
  for (int c = 0; c < 16; c++) {
    const int cb = c << 6;
    if (tid < 64) {
      u64 alive = validw[c] & ~removedw[c];
      u64 cur = alive;
      while (cur) {
        int i = __ffsll(cur) - 1;
        u64 row = intraAll[cb + i];                      // LDS broadcast read
        u64 lowmask = (i == 63) ? ~0ull : ((1ull << (i + 1)) - 1ull);
        row &= ~lowmask;
        alive &= ~row;
        cur &= ~row;
        cur &= cur - 1;
      }
      if (lane == 0) { keepw[c] = alive; aliveB = alive; }
    }
    __syncthreads();
    u64 am = aliveB;
    bool suppr = false;
    int j = ((c + 1) << 6) + tid;
    if (am && j < KPAD) {
      float jx0 = bxs[j][0], jy0 = bxs[j][1], jx1 = bxs[j][2], jy1 = bxs[j][3];
      float jarea = area_of(jx0, jy0, jx1, jy1);
      u64 m = am;
      int i = __ffsll(m) - 1; m &= m - 1;
      float px0 = bxs[cb + i][0], py0 = bxs[cb + i][1];
      float px1 = bxs[cb + i][2], py1 = bxs[cb + i][3];
      while (1) {
        int i2 = -1;
        float qx0, qy0, qx1, qy1;
        if (m) {                                          // prefetch next kept box
          i2 = __ffsll(m) - 1; m &= m - 1;
          qx0 = bxs[cb + i2][0]; qy0 = bxs[cb + i2][1];
          qx1 = bxs[cb + i2][2]; qy1 = bxs[cb + i2][3];
        }
        float parea = area_of(px0, py0, px1, py1);
        suppr |= iou_gt(px0, py0, px1, py1, parea, jx0, jy0, jx1, jy1, jarea);
        if (i2 < 0) break;
        px0 = qx0; py0 = qy0; px1 = qx1; py1 = qy1;
      }
    }
    u64 mask = __ballot(suppr);
    int word = c + 1 + w;
    if (lane == 0 && word < 16 && mask) atomicOr(&removedw[word], mask);
    __syncthreads();
  }

  // ---- stage 7: output ----
  if (tid < TOPK) {
    u64 kb = (keepw[tid >> 6] >> (tid & 63)) & 1ull;
    float f = (float)kb;
    size_t ob = (size_t)n * (TOPK * 5) + (size_t)tid * 5;
    out[ob + 0] = kb ? bxs[tid][0] : 0.0f;
    out[ob + 1] = kb ? bxs[tid][1] : 0.0f;
    out[ob + 2] = kb ? bxs[tid][2] : 0.0f;
    out[ob + 3] = kb ? bxs[tid][3] : 0.0f;
    out[ob + 4] = kb ? sc[tid] : 0.0f;
    out[(size_t)NIMG * TOPK * 5 + (size_t)n * TOPK + tid] = f;
  }
}

extern "C" void kernel_launch(void* const* d_in, const int* in_sizes, int n_in,
                              void* d_out, int out_size, void* d_ws, size_t ws_size,
                              hipStream_t stream) {
  const float* cls = (const float*)d_in[0];   // (32,1,384,384) f32
  const float* reg = (const float*)d_in[1];   // (32,4,384,384) f32
  float* out = (float*)d_out;                 // 160000 (out) + 32000 (keep) f32

  uint8_t* ws = (uint8_t*)d_ws;
  u32* pcnt = (u32*)(ws + PCNT_OFF);
  u32* phist = (u32*)(ws + PHIST_OFF);
  u64* pcand = (u64*)(ws + PCAND_OFF);

  scan_kernel<<<dim3(NBLK, NIMG), 256, 0, stream>>>(cls, phist, pcnt, pcand);
  mega_kernel<<<NIMG, 1024, 0, stream>>>(cls, reg, phist, pcnt, pcand, out);
}

// Round 4
// 231.196 us; speedup vs baseline: 1.7705x; 1.0282x over previous
//
#include <hip/hip_runtime.h>
#include <stdint.h>

#define NIMG 32
#define WID 384
#define HW 147456            // 384*384
#define TOPK 1000
#define KPAD 1024
#define NBINS 512
#define BIN_SCALEF 512.0f
#define SEGCAP 512
#define CANDCAP 2048
#define THRESH 0.05f
#define PREF_C 0.97f
#define PREF_BIN_MIN 497     // bin 497 edge = 0.970703 > 0.97f => prefilter superset
#define NMS_T 0.4f
#define NBLK 18              // scan blocks per image (18*2048 float4 = 147456 floats)

typedef unsigned long long u64;
typedef unsigned int u32;

// ---------------- workspace layout (bytes); everything fully overwritten each launch ----------------
#define PCNT_OFF 0                                   // 576 u32
#define PHIST_OFF 4096                               // 576*256 u32 = 589824
#define PCAND_OFF (PHIST_OFF + NIMG*NBLK*256*4)      // 576*512 u64 = 2359296  -> ends 2953216
#define SKEYS_OFF (PCAND_OFF + NIMG*NBLK*SEGCAP*8)   // 32*1024 u64 = 262144   -> ends 3215360
#define BOXES_OFF (SKEYS_OFF + NIMG*KPAD*8)          // 32*1024 float4 = 524288 -> ends 3739648
#define VALID_OFF (BOXES_OFF + NIMG*KPAD*16)         // 32*16 u64 = 4096        -> ends 3743744

// ---------- numerics helpers (fp-contraction-proof, matches numpy f32) ----------
__device__ __forceinline__ float area_of(float x0, float y0, float x1, float y1) {
  float a = fmaxf(x1 - x0, 0.0f) * fmaxf(y1 - y0, 0.0f);
  asm volatile("" : "+v"(a));
  return a;
}

__device__ __forceinline__ bool iou_gt(float ax0, float ay0, float ax1, float ay1, float aa,
                                       float bx0, float by0, float bx1, float by1, float ba) {
  float ix1 = fmaxf(ax0, bx0);
  float iy1 = fmaxf(ay0, by0);
  float ix2 = fminf(ax1, bx1);
  float iy2 = fminf(ay1, by1);
  float iw = fmaxf(ix2 - ix1, 0.0f);
  float ih = fmaxf(iy2 - iy1, 0.0f);
  float inter = iw * ih;
  asm volatile("" : "+v"(inter));
  float uni = fmaxf(aa + ba - inter, 1e-9f);
  return (inter / uni) > NMS_T;
}

__device__ __forceinline__ u64 shflxor64(u64 v, int m) {
  int lo = __shfl_xor((int)(u32)v, m, 64);
  int hi = __shfl_xor((int)(u32)(v >> 32), m, 64);
  return ((u64)(u32)hi << 32) | (u32)lo;
}

__device__ __forceinline__ u64 make_key(float s, u32 idx) {
  u32 ord = __float_as_uint(s) | 0x80000000u;   // s > 0 always here
  return ((u64)ord << 32) | (u32)(~idx);        // desc score, ties asc index (lax.top_k)
}

__device__ __forceinline__ int bin_of(float s) {
  int b = (int)(s * BIN_SCALEF);
  return b < 0 ? 0 : (b > NBINS - 1 ? NBINS - 1 : b);
}

// ---------- kernel 1: per-block private hist + prefilter collect (unchanged from r3) ----------
__global__ void scan_kernel(const float* __restrict__ cls, u32* __restrict__ phist,
                            u32* __restrict__ pcnt, u64* __restrict__ pcand) {
  __shared__ u32 h[NBINS];
  __shared__ u64 lbuf[SEGCAP];
  __shared__ u32 lcnt;
  const int n = blockIdx.y;
  const int tid = threadIdx.x;
  const int lane = tid & 63;
  h[tid] = 0; h[tid + 256] = 0;
  if (tid == 0) lcnt = 0;
  __syncthreads();

  const float4* src = (const float4*)(cls + (size_t)n * HW) + blockIdx.x * 2048;
  float4 A[8];
#pragma unroll
  for (int v = 0; v < 8; v++) A[v] = src[tid + v * 256];

  const u64 ltmask = (1ull << lane) - 1ull;
#pragma unroll
  for (int v = 0; v < 8; v++) {
    float ss[4] = {A[v].x, A[v].y, A[v].z, A[v].w};
#pragma unroll
    for (int c = 0; c < 4; c++) {
      float s = ss[c];
      if (s > THRESH) atomicAdd(&h[bin_of(s)], 1u);        // LDS atomic only
      bool pc = s > PREF_C;
      u64 m = __ballot(pc);
      if (m) {
        int ldr = __ffsll(m) - 1;
        u32 wb = 0;
        if (lane == ldr) wb = atomicAdd(&lcnt, (u32)__popcll(m));
        wb = (u32)__shfl((int)wb, ldr, 64);
        if (pc) {
          u32 pos = wb + (u32)__popcll(m & ltmask);
          if (pos < SEGCAP) lbuf[pos] = make_key(s, (u32)((blockIdx.x * 2048 + tid + v * 256) * 4 + c));
        }
      }
    }
  }
  __syncthreads();
  const int seg = n * NBLK + blockIdx.x;
  phist[seg * 256 + tid] = (h[2 * tid] & 0xFFFFu) | (h[2 * tid + 1] << 16);
  if (tid == 0) pcnt[seg] = (lcnt > SEGCAP) ? 0xFFFFFFFFu : lcnt;
  u32 c = lcnt < SEGCAP ? lcnt : (u32)SEGCAP;
  u64* pc = pcand + (size_t)seg * SEGCAP;
  for (u32 i = tid; i < c; i += 256) pc[i] = lbuf[i];
}

// reg-chain bitonic levels for stage k (jstart <= 64, via shuffles, no barriers)
#define REGCHAIN(K, JSTART) do {                                            \
    const bool desc_ = ((tid & ((K) >> 1)) == 0);                           \
    for (int j_ = (JSTART); j_ >= 2; j_ >>= 1) {                            \
      int h_ = j_ >> 1;                                                     \
      bool low_ = (tid & h_) == 0;                                          \
      u64 p0_ = shflxor64(e0, h_), p1_ = shflxor64(e1, h_);                 \
      bool tm_ = (low_ == desc_);                                           \
      e0 = tm_ ? (e0 > p0_ ? e0 : p0_) : (e0 < p0_ ? e0 : p0_);             \
      e1 = tm_ ? (e1 > p1_ ? e1 : p1_) : (e1 < p1_ ? e1 : p1_);             \
    }                                                                       \
    { u64 lo_ = e0 < e1 ? e0 : e1, hi_ = e0 < e1 ? e1 : e0;                 \
      e0 = desc_ ? hi_ : lo_; e1 = desc_ ? lo_ : hi_; }                     \
  } while (0)

// ---------- kernel 2: hist-reduce + threshold + filter + sort; write top-1024 keys ----------
__global__ __launch_bounds__(1024) void sort_kernel(const float* __restrict__ cls,
                                                    const u32* __restrict__ phist,
                                                    const u32* __restrict__ pcnt,
                                                    const u64* __restrict__ pcand,
                                                    u64* __restrict__ skeys) {
  __shared__ u64 skey[CANDCAP];        // 16 KB
  __shared__ u32 bs[NBINS];
  __shared__ u32 stmp[64];
  __shared__ int stbin;
  __shared__ u32 sflag, sfc;

  const int n = blockIdx.x;
  const int tid = threadIdx.x;
  const int lane = tid & 63;
  const u64 ltmask = (1ull << lane) - 1ull;

  if (tid < 256) {
    u32 lo = 0, hi = 0;
#pragma unroll
    for (int b = 0; b < NBLK; b++) {
      u32 p = phist[(size_t)(n * NBLK + b) * 256 + tid];
      lo += p & 0xFFFFu; hi += p >> 16;
    }
    bs[2 * tid] = lo; bs[2 * tid + 1] = hi;
  }
  if (tid == 0) {
    u32 f = 0;
    for (int b = 0; b < NBLK; b++) if (pcnt[n * NBLK + b] == 0xFFFFFFFFu) f = 1;
    sflag = f; sfc = 0;
  }
  skey[tid] = 0ull; skey[tid + 1024] = 0ull;
  __syncthreads();

  // exact threshold bin (wave 0)
  if (tid < 64) {
    u32 cs = 0;
#pragma unroll
    for (int k2 = 0; k2 < 8; k2++) cs += bs[lane * 8 + k2];
    u32 s = cs;
#pragma unroll
    for (int d = 1; d < 64; d <<= 1) {
      u32 v = (u32)__shfl_down((int)s, d, 64);
      if (lane + d < 64) s += v;
    }
    stmp[lane] = s;
    u64 mask = __ballot(s >= TOPK);
    if (lane == 0) {
      int t = 0;
      if (mask) {
        int L = 63 - __clzll(mask);
        u32 acc = (L < 63) ? stmp[L + 1] : 0;
        for (int b = L * 8 + 7; b >= L * 8; b--) {
          acc += bs[b];
          if (acc >= TOPK) { t = b; break; }
        }
      }
      stbin = t;
      if (t < PREF_BIN_MIN) sflag = 1;
    }
  }
  __syncthreads();

  const int t = stbin;
  if (sflag == 0) {
    for (int bp = 0; bp < 9; bp++) {
      int seg = bp * 2 + (tid >> 9);
      int i = tid & 511;
      u32 c = pcnt[n * NBLK + seg];
      bool p = false; u64 key = 0;
      if (i < (int)c) {
        key = pcand[(size_t)(n * NBLK + seg) * SEGCAP + i];
        float s = __uint_as_float((u32)(key >> 32) & 0x7FFFFFFFu);
        p = bin_of(s) >= t;
      }
      u64 m = __ballot(p);
      if (m) {
        int ldr = __ffsll(m) - 1;
        u32 wb = 0;
        if (lane == ldr) wb = atomicAdd(&sfc, (u32)__popcll(m));
        wb = (u32)__shfl((int)wb, ldr, 64);
        if (p) { u32 pos = wb + (u32)__popcll(m & ltmask); if (pos < CANDCAP) skey[pos] = key; }
      }
    }
  } else {
    // exact fallback: rescan this image directly (dead path for bench input)
    const float* ci = cls + (size_t)n * HW;
    for (int base = 0; base < HW; base += 1024) {
      int i = base + tid;
      float s = ci[i];
      bool p = (s > THRESH) && (bin_of(s) >= t);
      u64 m = __ballot(p);
      if (m) {
        int ldr = __ffsll(m) - 1;
        u32 wb = 0;
        if (lane == ldr) wb = atomicAdd(&sfc, (u32)__popcll(m));
        wb = (u32)__shfl((int)wb, ldr, 64);
        if (p) { u32 pos = wb + (u32)__popcll(m & ltmask); if (pos < CANDCAP) skey[pos] = make_key(s, (u32)i); }
      }
    }
  }
  __syncthreads();

  // hybrid bitonic sort (2048 keys, 2/thread)
  {
    u64 e0 = skey[2 * tid], e1 = skey[2 * tid + 1];
    REGCHAIN(2, 1); REGCHAIN(4, 2); REGCHAIN(8, 4); REGCHAIN(16, 8);
    REGCHAIN(32, 16); REGCHAIN(64, 32); REGCHAIN(128, 64);
    for (int k = 256; k <= CANDCAP; k <<= 1) {
      skey[2 * tid] = e0; skey[2 * tid + 1] = e1;
      __syncthreads();
      for (int j = k >> 1; j >= 128; j >>= 1) {
        int i = ((tid & ~(j - 1)) << 1) | (tid & (j - 1));
        u64 a = skey[i], b = skey[i + j];
        bool desc = ((i & k) == 0);
        if (desc ? (a < b) : (a > b)) { skey[i] = b; skey[i + j] = a; }
        __syncthreads();
      }
      e0 = skey[2 * tid]; e1 = skey[2 * tid + 1];
      REGCHAIN(k, 64);
    }
    skey[2 * tid] = e0; skey[2 * tid + 1] = e1;
    __syncthreads();
  }

  // write top-1024 keys (coalesced)
  if (tid < KPAD) skeys[(size_t)n * KPAD + tid] = skey[tid];
}

// ---------- kernel 3: parallel gather + decode (256 blocks — spreads scattered loads chip-wide) ----------
__global__ void decode_kernel(const float* __restrict__ reg, const u64* __restrict__ skeys,
                              float4* __restrict__ gboxes, u64* __restrict__ gvalid) {
  const int n = blockIdx.y;
  const int s8 = blockIdx.x;            // slice 0..7
  const int tid = threadIdx.x;          // 0..127
  const int k = s8 * 128 + tid;
  u64 key = skeys[(size_t)n * KPAD + k];
  float x0 = 0.f, y0 = 0.f, x1 = 0.f, y1 = 0.f;
  bool val = false;
  if (key != 0ull && k < TOPK) {
    u32 idx = ~(u32)(key & 0xFFFFFFFFull);
    float sv = __uint_as_float((u32)(key >> 32) & 0x7FFFFFFFu);
    int iy = (int)idx / WID;
    int ix = (int)idx - iy * WID;
    float xx = (float)ix * 4.0f;
    float yy = (float)iy * 4.0f;
    const float* rb = reg + (size_t)n * 4 * HW;
    float r0 = rb[idx];
    float r1 = rb[HW + idx];
    float r2 = rb[2 * HW + idx];
    float r3 = rb[3 * HW + idx];
    y0 = yy - r0; x1 = xx + r1; y1 = yy + r2; x0 = xx - r3;
    float wsz = x1 - x0, hsz = y1 - y0;
    val = (sv > THRESH) && (wsz >= 0.0f) && (hsz >= 0.0f);
  }
  gboxes[(size_t)n * KPAD + k] = make_float4(x0, y0, x1, y1);
  u64 m = __ballot(val);
  if ((tid & 63) == 0) gvalid[n * 16 + (k >> 6)] = m;
}

// ---------- kernel 4: NMS (readlane-based serial resolve) + output ----------
__global__ __launch_bounds__(1024) void nms_kernel(const float4* __restrict__ gboxes,
                                                   const u64* __restrict__ gvalid,
                                                   const u64* __restrict__ skeys,
                                                   float* __restrict__ out) {
  __shared__ float bxs[KPAD][4];       // 16 KB
  __shared__ u64 intraAll[KPAD];       // 8 KB
  __shared__ u64 validw[16], removedw[16], keepw[16];
  __shared__ u64 aliveB;

  const int n = blockIdx.x;
  const int tid = threadIdx.x;
  const int lane = tid & 63;
  const int w = tid >> 6;

  u64 mykey = skeys[(size_t)n * KPAD + tid];          // score for output
  float4 b4 = gboxes[(size_t)n * KPAD + tid];
  bxs[tid][0] = b4.x; bxs[tid][1] = b4.y; bxs[tid][2] = b4.z; bxs[tid][3] = b4.w;
  if (tid < 16) { validw[tid] = gvalid[n * 16 + tid]; removedw[tid] = 0; keepw[tid] = 0; }
  __syncthreads();

  // precompute ALL intra-chunk suppression rows (16 waves || 16 chunks)
  {
    const int cb = w << 6;
    float mx0 = bxs[cb + lane][0], my0 = bxs[cb + lane][1];
    float mx1 = bxs[cb + lane][2], my1 = bxs[cb + lane][3];
    float marea = area_of(mx0, my0, mx1, my1);
    for (int l = 0; l < 64; l++) {
      float lx0 = bxs[cb + l][0], ly0 = bxs[cb + l][1];
      float lx1 = bxs[cb + l][2], ly1 = bxs[cb + l][3];
      float larea = area_of(lx0, ly0, lx1, ly1);
      bool pred = iou_gt(lx0, ly0, lx1, ly1, larea, mx0, my0, mx1, my1, marea);
      u64 row = __ballot(pred);
      if (lane == l) intraAll[cb + l] = row;
    }
  }
  __syncthreads();

  // sequential chunk scan
  for (int c = 0; c < 16; c++) {
    const int cb = c << 6;
    if (tid < 64) {
      // lane i holds row i in VGPRs; resolve loop is scalar (s_ff1 + v_readlane)
      u64 rowv = intraAll[cb + lane];
      u32 rlo = (u32)rowv, rhi = (u32)(rowv >> 32);
      u64 a64 = validw[c] & ~removedw[c];
      u32 alo = __builtin_amdgcn_readfirstlane((u32)a64);
      u32 ahi = __builtin_amdgcn_readfirstlane((u32)(a64 >> 32));
      u64 alive = ((u64)ahi << 32) | alo;
      u64 cur = alive;
      while (cur) {
        int i = __ffsll(cur) - 1;
        u32 rl = __builtin_amdgcn_readlane(rlo, i);
        u32 rh = __builtin_amdgcn_readlane(rhi, i);
        u64 row = ((u64)rh << 32) | rl;
        u64 lowmask = (i == 63) ? ~0ull : ((1ull << (i + 1)) - 1ull);
        row &= ~lowmask;
        alive &= ~row;
        cur &= ~row;
        cur &= cur - 1;
      }
      if (lane == 0) { keepw[c] = alive; aliveB = alive; }
    }
    __syncthreads();
    u64 am = aliveB;
    bool suppr = false;
    int j = ((c + 1) << 6) + tid;
    if (am && j < KPAD) {
      float jx0 = bxs[j][0], jy0 = bxs[j][1], jx1 = bxs[j][2], jy1 = bxs[j][3];
      float jarea = area_of(jx0, jy0, jx1, jy1);
      u64 m = am;
      int i = __ffsll(m) - 1; m &= m - 1;
      float px0 = bxs[cb + i][0], py0 = bxs[cb + i][1];
      float px1 = bxs[cb + i][2], py1 = bxs[cb + i][3];
      while (1) {
        int i2 = -1;
        float qx0, qy0, qx1, qy1;
        if (m) {
          i2 = __ffsll(m) - 1; m &= m - 1;
          qx0 = bxs[cb + i2][0]; qy0 = bxs[cb + i2][1];
          qx1 = bxs[cb + i2][2]; qy1 = bxs[cb + i2][3];
        }
        float parea = area_of(px0, py0, px1, py1);
        suppr |= iou_gt(px0, py0, px1, py1, parea, jx0, jy0, jx1, jy1, jarea);
        if (i2 < 0) break;
        px0 = qx0; py0 = qy0; px1 = qx1; py1 = qy1;
      }
    }
    u64 mask = __ballot(suppr);
    int word = c + 1 + w;
    if (lane == 0 && word < 16 && mask) atomicOr(&removedw[word], mask);
    __syncthreads();
  }

  // output
  if (tid < TOPK) {
    u64 kb = (keepw[tid >> 6] >> (tid & 63)) & 1ull;
    float f = (float)kb;
    float s = __uint_as_float((u32)(mykey >> 32) & 0x7FFFFFFFu);
    size_t ob = (size_t)n * (TOPK * 5) + (size_t)tid * 5;
    out[ob + 0] = kb ? bxs[tid][0] : 0.0f;
    out[ob + 1] = kb ? bxs[tid][1] : 0.0f;
    out[ob + 2] = kb ? bxs[tid][2] : 0.0f;
    out[ob + 3] = kb ? bxs[tid][3] : 0.0f;
    out[ob + 4] = kb ? s : 0.0f;
    out[(size_t)NIMG * TOPK * 5 + (size_t)n * TOPK + tid] = f;
  }
}

extern "C" void kernel_launch(void* const* d_in, const int* in_sizes, int n_in,
                              void* d_out, int out_size, void* d_ws, size_t ws_size,
                              hipStream_t stream) {
  const float* cls = (const float*)d_in[0];   // (32,1,384,384) f32
  const float* reg = (const float*)d_in[1];   // (32,4,384,384) f32
  float* out = (float*)d_out;                 // 160000 (out) + 32000 (keep) f32

  uint8_t* ws = (uint8_t*)d_ws;
  u32* pcnt = (u32*)(ws + PCNT_OFF);
  u32* phist = (u32*)(ws + PHIST_OFF);
  u64* pcand = (u64*)(ws + PCAND_OFF);
  u64* skeys = (u64*)(ws + SKEYS_OFF);
  float4* gboxes = (float4*)(ws + BOXES_OFF);
  u64* gvalid = (u64*)(ws + VALID_OFF);

  scan_kernel<<<dim3(NBLK, NIMG), 256, 0, stream>>>(cls, phist, pcnt, pcand);
  sort_kernel<<<NIMG, 1024, 0, stream>>>(cls, phist, pcnt, pcand, skeys);
  decode_kernel<<<dim3(8, NIMG), 128, 0, stream>>>(reg, skeys, gboxes, gvalid);
  nms_kernel<<<NIMG, 1024, 0, stream>>>(gboxes, gvalid, skeys, out);
}

// Round 5
// 213.654 us; speedup vs baseline: 1.9159x; 1.0821x over previous
//
#include <hip/hip_runtime.h>
#include <stdint.h>

#define NIMG 32
#define WID 384
#define HW 147456            // 384*384
#define TOPK 1000
#define KPAD 1024
#define NBINS 512
#define BIN_SCALEF 512.0f
#define SEGCAP 512
#define CANDCAP 2048
#define THRESH 0.05f
#define PREF_C 0.97f
#define PREF_BIN_MIN 497     // bin 497 edge = 0.970703 > 0.97f => prefilter superset
#define NMS_T 0.4f
#define NBLK 18              // scan blocks per image (18*2048 float4 = 147456 floats)

typedef unsigned long long u64;
typedef unsigned int u32;

// ---------------- workspace layout (bytes); everything fully overwritten each launch ----------------
#define PCNT_OFF 0                                   // 576 u32
#define PHIST_OFF 4096                               // 576*256 u32 = 589824 -> ends 593920
#define PCAND_OFF (PHIST_OFF + NIMG*NBLK*256*4)      // 576*512 u64 = 2359296 -> ends 2953216
#define SKEYS_OFF (PCAND_OFF + NIMG*NBLK*SEGCAP*8)   // 32*1024 u64 = 262144  -> ends 3215360
#define BOXES_OFF (SKEYS_OFF + NIMG*KPAD*8)          // 32*1024 float4 = 524288 -> ends 3739648
#define VALID_OFF (BOXES_OFF + NIMG*KPAD*16)         // 32*16 u64 = 4096       -> ends 3743744
#define MTRX_OFF (VALID_OFF + NIMG*16*8)             // 32*16*1024 u64 = 4 MB  -> ends 7938048

// ---------- numerics helpers (fp-contraction-proof, matches numpy f32) ----------
__device__ __forceinline__ float area_of(float x0, float y0, float x1, float y1) {
  float a = fmaxf(x1 - x0, 0.0f) * fmaxf(y1 - y0, 0.0f);
  asm volatile("" : "+v"(a));
  return a;
}

__device__ __forceinline__ bool iou_gt(float ax0, float ay0, float ax1, float ay1, float aa,
                                       float bx0, float by0, float bx1, float by1, float ba) {
  float ix1 = fmaxf(ax0, bx0);
  float iy1 = fmaxf(ay0, by0);
  float ix2 = fminf(ax1, bx1);
  float iy2 = fminf(ay1, by1);
  float iw = fmaxf(ix2 - ix1, 0.0f);
  float ih = fmaxf(iy2 - iy1, 0.0f);
  float inter = iw * ih;
  asm volatile("" : "+v"(inter));
  float uni = fmaxf(aa + ba - inter, 1e-9f);
  return (inter / uni) > NMS_T;
}

__device__ __forceinline__ u64 shflxor64(u64 v, int m) {
  int lo = __shfl_xor((int)(u32)v, m, 64);
  int hi = __shfl_xor((int)(u32)(v >> 32), m, 64);
  return ((u64)(u32)hi << 32) | (u32)lo;
}

__device__ __forceinline__ u64 make_key(float s, u32 idx) {
  u32 ord = __float_as_uint(s) | 0x80000000u;   // s > 0 always here
  return ((u64)ord << 32) | (u32)(~idx);        // desc score, ties asc index (lax.top_k)
}

__device__ __forceinline__ int bin_of(float s) {
  int b = (int)(s * BIN_SCALEF);
  return b < 0 ? 0 : (b > NBINS - 1 ? NBINS - 1 : b);
}

// ---------- kernel 1: per-block private hist + prefilter collect (unchanged) ----------
__global__ void scan_kernel(const float* __restrict__ cls, u32* __restrict__ phist,
                            u32* __restrict__ pcnt, u64* __restrict__ pcand) {
  __shared__ u32 h[NBINS];
  __shared__ u64 lbuf[SEGCAP];
  __shared__ u32 lcnt;
  const int n = blockIdx.y;
  const int tid = threadIdx.x;
  const int lane = tid & 63;
  h[tid] = 0; h[tid + 256] = 0;
  if (tid == 0) lcnt = 0;
  __syncthreads();

  const float4* src = (const float4*)(cls + (size_t)n * HW) + blockIdx.x * 2048;
  float4 A[8];
#pragma unroll
  for (int v = 0; v < 8; v++) A[v] = src[tid + v * 256];

  const u64 ltmask = (1ull << lane) - 1ull;
#pragma unroll
  for (int v = 0; v < 8; v++) {
    float ss[4] = {A[v].x, A[v].y, A[v].z, A[v].w};
#pragma unroll
    for (int c = 0; c < 4; c++) {
      float s = ss[c];
      if (s > THRESH) atomicAdd(&h[bin_of(s)], 1u);        // LDS atomic only
      bool pc = s > PREF_C;
      u64 m = __ballot(pc);
      if (m) {
        int ldr = __ffsll(m) - 1;
        u32 wb = 0;
        if (lane == ldr) wb = atomicAdd(&lcnt, (u32)__popcll(m));
        wb = (u32)__shfl((int)wb, ldr, 64);
        if (pc) {
          u32 pos = wb + (u32)__popcll(m & ltmask);
          if (pos < SEGCAP) lbuf[pos] = make_key(s, (u32)((blockIdx.x * 2048 + tid + v * 256) * 4 + c));
        }
      }
    }
  }
  __syncthreads();
  const int seg = n * NBLK + blockIdx.x;
  phist[seg * 256 + tid] = (h[2 * tid] & 0xFFFFu) | (h[2 * tid + 1] << 16);
  if (tid == 0) pcnt[seg] = (lcnt > SEGCAP) ? 0xFFFFFFFFu : lcnt;
  u32 c = lcnt < SEGCAP ? lcnt : (u32)SEGCAP;
  u64* pc = pcand + (size_t)seg * SEGCAP;
  for (u32 i = tid; i < c; i += 256) pc[i] = lbuf[i];
}

// reg-chain bitonic levels for stage k (jstart <= 64, via shuffles, no barriers)
#define REGCHAIN(K, JSTART) do {                                            \
    const bool desc_ = ((tid & ((K) >> 1)) == 0);                           \
    for (int j_ = (JSTART); j_ >= 2; j_ >>= 1) {                            \
      int h_ = j_ >> 1;                                                     \
      bool low_ = (tid & h_) == 0;                                          \
      u64 p0_ = shflxor64(e0, h_), p1_ = shflxor64(e1, h_);                 \
      bool tm_ = (low_ == desc_);                                           \
      e0 = tm_ ? (e0 > p0_ ? e0 : p0_) : (e0 < p0_ ? e0 : p0_);             \
      e1 = tm_ ? (e1 > p1_ ? e1 : p1_) : (e1 < p1_ ? e1 : p1_);             \
    }                                                                       \
    { u64 lo_ = e0 < e1 ? e0 : e1, hi_ = e0 < e1 ? e1 : e0;                 \
      e0 = desc_ ? hi_ : lo_; e1 = desc_ ? lo_ : hi_; }                     \
  } while (0)

// ---------- kernel 2: hist-reduce + threshold + filter + sort; write top-1024 keys (unchanged) ----------
__global__ __launch_bounds__(1024) void sort_kernel(const float* __restrict__ cls,
                                                    const u32* __restrict__ phist,
                                                    const u32* __restrict__ pcnt,
                                                    const u64* __restrict__ pcand,
                                                    u64* __restrict__ skeys) {
  __shared__ u64 skey[CANDCAP];
  __shared__ u32 bs[NBINS];
  __shared__ u32 stmp[64];
  __shared__ int stbin;
  __shared__ u32 sflag, sfc;

  const int n = blockIdx.x;
  const int tid = threadIdx.x;
  const int lane = tid & 63;
  const u64 ltmask = (1ull << lane) - 1ull;

  if (tid < 256) {
    u32 lo = 0, hi = 0;
#pragma unroll
    for (int b = 0; b < NBLK; b++) {
      u32 p = phist[(size_t)(n * NBLK + b) * 256 + tid];
      lo += p & 0xFFFFu; hi += p >> 16;
    }
    bs[2 * tid] = lo; bs[2 * tid + 1] = hi;
  }
  if (tid == 0) {
    u32 f = 0;
    for (int b = 0; b < NBLK; b++) if (pcnt[n * NBLK + b] == 0xFFFFFFFFu) f = 1;
    sflag = f; sfc = 0;
  }
  skey[tid] = 0ull; skey[tid + 1024] = 0ull;
  __syncthreads();

  if (tid < 64) {
    u32 cs = 0;
#pragma unroll
    for (int k2 = 0; k2 < 8; k2++) cs += bs[lane * 8 + k2];
    u32 s = cs;
#pragma unroll
    for (int d = 1; d < 64; d <<= 1) {
      u32 v = (u32)__shfl_down((int)s, d, 64);
      if (lane + d < 64) s += v;
    }
    stmp[lane] = s;
    u64 mask = __ballot(s >= TOPK);
    if (lane == 0) {
      int t = 0;
      if (mask) {
        int L = 63 - __clzll(mask);
        u32 acc = (L < 63) ? stmp[L + 1] : 0;
        for (int b = L * 8 + 7; b >= L * 8; b--) {
          acc += bs[b];
          if (acc >= TOPK) { t = b; break; }
        }
      }
      stbin = t;
      if (t < PREF_BIN_MIN) sflag = 1;
    }
  }
  __syncthreads();

  const int t = stbin;
  if (sflag == 0) {
    for (int bp = 0; bp < 9; bp++) {
      int seg = bp * 2 + (tid >> 9);
      int i = tid & 511;
      u32 c = pcnt[n * NBLK + seg];
      bool p = false; u64 key = 0;
      if (i < (int)c) {
        key = pcand[(size_t)(n * NBLK + seg) * SEGCAP + i];
        float s = __uint_as_float((u32)(key >> 32) & 0x7FFFFFFFu);
        p = bin_of(s) >= t;
      }
      u64 m = __ballot(p);
      if (m) {
        int ldr = __ffsll(m) - 1;
        u32 wb = 0;
        if (lane == ldr) wb = atomicAdd(&sfc, (u32)__popcll(m));
        wb = (u32)__shfl((int)wb, ldr, 64);
        if (p) { u32 pos = wb + (u32)__popcll(m & ltmask); if (pos < CANDCAP) skey[pos] = key; }
      }
    }
  } else {
    // exact fallback: rescan this image directly (dead path for bench input)
    const float* ci = cls + (size_t)n * HW;
    for (int base = 0; base < HW; base += 1024) {
      int i = base + tid;
      float s = ci[i];
      bool p = (s > THRESH) && (bin_of(s) >= t);
      u64 m = __ballot(p);
      if (m) {
        int ldr = __ffsll(m) - 1;
        u32 wb = 0;
        if (lane == ldr) wb = atomicAdd(&sfc, (u32)__popcll(m));
        wb = (u32)__shfl((int)wb, ldr, 64);
        if (p) { u32 pos = wb + (u32)__popcll(m & ltmask); if (pos < CANDCAP) skey[pos] = make_key(s, (u32)i); }
      }
    }
  }
  __syncthreads();

  {
    u64 e0 = skey[2 * tid], e1 = skey[2 * tid + 1];
    REGCHAIN(2, 1); REGCHAIN(4, 2); REGCHAIN(8, 4); REGCHAIN(16, 8);
    REGCHAIN(32, 16); REGCHAIN(64, 32); REGCHAIN(128, 64);
    for (int k = 256; k <= CANDCAP; k <<= 1) {
      skey[2 * tid] = e0; skey[2 * tid + 1] = e1;
      __syncthreads();
      for (int j = k >> 1; j >= 128; j >>= 1) {
        int i = ((tid & ~(j - 1)) << 1) | (tid & (j - 1));
        u64 a = skey[i], b = skey[i + j];
        bool desc = ((i & k) == 0);
        if (desc ? (a < b) : (a > b)) { skey[i] = b; skey[i + j] = a; }
        __syncthreads();
      }
      e0 = skey[2 * tid]; e1 = skey[2 * tid + 1];
      REGCHAIN(k, 64);
    }
    skey[2 * tid] = e0; skey[2 * tid + 1] = e1;
    __syncthreads();
  }

  if (tid < KPAD) skeys[(size_t)n * KPAD + tid] = skey[tid];
}

// ---------- kernel 3: parallel gather + decode (unchanged) ----------
__global__ void decode_kernel(const float* __restrict__ reg, const u64* __restrict__ skeys,
                              float4* __restrict__ gboxes, u64* __restrict__ gvalid) {
  const int n = blockIdx.y;
  const int s8 = blockIdx.x;
  const int tid = threadIdx.x;
  const int k = s8 * 128 + tid;
  u64 key = skeys[(size_t)n * KPAD + k];
  float x0 = 0.f, y0 = 0.f, x1 = 0.f, y1 = 0.f;
  bool val = false;
  if (key != 0ull && k < TOPK) {
    u32 idx = ~(u32)(key & 0xFFFFFFFFull);
    float sv = __uint_as_float((u32)(key >> 32) & 0x7FFFFFFFu);
    int iy = (int)idx / WID;
    int ix = (int)idx - iy * WID;
    float xx = (float)ix * 4.0f;
    float yy = (float)iy * 4.0f;
    const float* rb = reg + (size_t)n * 4 * HW;
    float r0 = rb[idx];
    float r1 = rb[HW + idx];
    float r2 = rb[2 * HW + idx];
    float r3 = rb[3 * HW + idx];
    y0 = yy - r0; x1 = xx + r1; y1 = yy + r2; x0 = xx - r3;
    float wsz = x1 - x0, hsz = y1 - y0;
    val = (sv > THRESH) && (wsz >= 0.0f) && (hsz >= 0.0f);
  }
  gboxes[(size_t)n * KPAD + k] = make_float4(x0, y0, x1, y1);
  u64 m = __ballot(val);
  if ((tid & 63) == 0) gvalid[n * 16 + (k >> 6)] = m;
}

// ---------- kernel 4: chip-wide suppression bit-matrix ----------
// M[n][w][i] bit j = iou(box_i, box_{64w+j}) > NMS_T.  Only w <= i>>6 (lower word-triangle)
// is computed/consumed; resolve uses symmetry for cross-chunk suppression.
__global__ __launch_bounds__(256) void matrix_kernel(const float4* __restrict__ gboxes,
                                                     u64* __restrict__ M) {
  __shared__ float rb[64][4];
  __shared__ float ra[64];
  const int cw = blockIdx.x;       // row chunk 0..15
  const int n  = blockIdx.y;
  const int tid = threadIdx.x;
  const int q = tid >> 6, lane = tid & 63;
  if (tid < 64) {
    float4 b = gboxes[(size_t)n * KPAD + cw * 64 + tid];
    rb[tid][0] = b.x; rb[tid][1] = b.y; rb[tid][2] = b.z; rb[tid][3] = b.w;
    ra[tid] = area_of(b.x, b.y, b.z, b.w);
  }
  __syncthreads();
  for (int w = 0; w <= cw; w++) {
    float4 cbx = gboxes[(size_t)n * KPAD + w * 64 + lane];
    float carea = area_of(cbx.x, cbx.y, cbx.z, cbx.w);
    u32 alo = 0, ahi = 0;
#pragma unroll
    for (int r = 0; r < 16; r++) {
      int i = q * 16 + r;          // row within chunk
      float lx0 = rb[i][0], ly0 = rb[i][1], lx1 = rb[i][2], ly1 = rb[i][3];
      float larea = ra[i];
      bool pred = iou_gt(lx0, ly0, lx1, ly1, larea, cbx.x, cbx.y, cbx.z, cbx.w, carea);
      u64 m = __ballot(pred);
      if (lane == r) { alo = (u32)m; ahi = (u32)(m >> 32); }   // stash row r into lane r
    }
    if (lane < 16)
      M[(((size_t)n * 16 + w) << 10) + cw * 64 + q * 16 + lane] = ((u64)ahi << 32) | alo;
  }
}

// ---------- kernel 5: single-wave greedy resolve (pure bit-ops) + output ----------
__global__ __launch_bounds__(64) void resolve_kernel(const float4* __restrict__ gboxes,
                                                     const u64* __restrict__ gvalid,
                                                     const u64* __restrict__ skeys,
                                                     const u64* __restrict__ M,
                                                     float* __restrict__ out) {
  __shared__ u64 keepsh[16];
  __shared__ u64 srem[16];
  __shared__ u64 sval[16];
  const int n = blockIdx.x;
  const int lane = threadIdx.x;
  if (lane < 16) { sval[lane] = gvalid[n * 16 + lane]; srem[lane] = 0ull; keepsh[lane] = 0ull; }
  __syncthreads();

  for (int c = 0; c < 16; c++) {
    const u64* Mc = M + (((size_t)n * 16 + c) << 10);
    u64 wc = Mc[c * 64 + lane];                 // diagonal word: intra-chunk rows
    u64 row[16];
#pragma unroll
    for (int k = 0; k < 16; k++)
      row[k] = (k > c) ? Mc[k * 64 + lane] : 0ull;   // symmetric: suppression of later cols by chunk c

    u64 alive;
    {
      u64 a = sval[c] & ~srem[c];
      u32 alo2 = __builtin_amdgcn_readfirstlane((u32)a);
      u32 ahi2 = __builtin_amdgcn_readfirstlane((u32)(a >> 32));
      alive = ((u64)ahi2 << 32) | alo2;
    }
    // serial intra resolve via readlane (lane i holds row i of the diagonal block)
    u32 rlo = (u32)wc, rhi = (u32)(wc >> 32);
    u64 cur = alive;
    while (cur) {
      int i = __ffsll(cur) - 1;
      u32 rl = __builtin_amdgcn_readlane(rlo, i);
      u32 rh = __builtin_amdgcn_readlane(rhi, i);
      u64 rowi = ((u64)rh << 32) | rl;
      u64 lowmask = (i == 63) ? ~0ull : ((1ull << (i + 1)) - 1ull);
      rowi &= ~lowmask;                         // suppress only j > i
      alive &= ~rowi;
      cur &= ~rowi;
      cur &= cur - 1;
    }
    if (lane == 0) keepsh[c] = alive;
    const u64 K = alive;
    // cross-chunk update: col x suppressed iff any kept row of chunk c hits it (symmetry)
#pragma unroll
    for (int k = 1; k < 16; k++) {
      if (k > c) {
        bool sup = (row[k] & K) != 0ull;
        u64 mres = __ballot(sup);
        if (lane == 0) srem[k] |= mres;
      }
    }
    __syncthreads();   // single wave: cheap; orders LDS RMW for next chunk
  }

  // output: 16 iterations of 64 lanes
#pragma unroll
  for (int c16 = 0; c16 < 16; c16++) {
    int k = c16 * 64 + lane;
    u64 kb = (keepsh[c16] >> lane) & 1ull;
    float4 b = gboxes[(size_t)n * KPAD + k];
    u64 key = skeys[(size_t)n * KPAD + k];
    float s = __uint_as_float((u32)(key >> 32) & 0x7FFFFFFFu);
    if (k < TOPK) {
      float f = (float)kb;
      size_t ob = (size_t)n * (TOPK * 5) + (size_t)k * 5;
      out[ob + 0] = kb ? b.x : 0.0f;
      out[ob + 1] = kb ? b.y : 0.0f;
      out[ob + 2] = kb ? b.z : 0.0f;
      out[ob + 3] = kb ? b.w : 0.0f;
      out[ob + 4] = kb ? s : 0.0f;
      out[(size_t)NIMG * TOPK * 5 + (size_t)n * TOPK + k] = f;
    }
  }
}

extern "C" void kernel_launch(void* const* d_in, const int* in_sizes, int n_in,
                              void* d_out, int out_size, void* d_ws, size_t ws_size,
                              hipStream_t stream) {
  const float* cls = (const float*)d_in[0];   // (32,1,384,384) f32
  const float* reg = (const float*)d_in[1];   // (32,4,384,384) f32
  float* out = (float*)d_out;                 // 160000 (out) + 32000 (keep) f32

  uint8_t* ws = (uint8_t*)d_ws;
  u32* pcnt = (u32*)(ws + PCNT_OFF);
  u32* phist = (u32*)(ws + PHIST_OFF);
  u64* pcand = (u64*)(ws + PCAND_OFF);
  u64* skeys = (u64*)(ws + SKEYS_OFF);
  float4* gboxes = (float4*)(ws + BOXES_OFF);
  u64* gvalid = (u64*)(ws + VALID_OFF);
  u64* M = (u64*)(ws + MTRX_OFF);

  scan_kernel<<<dim3(NBLK, NIMG), 256, 0, stream>>>(cls, phist, pcnt, pcand);
  sort_kernel<<<NIMG, 1024, 0, stream>>>(cls, phist, pcnt, pcand, skeys);
  decode_kernel<<<dim3(8, NIMG), 128, 0, stream>>>(reg, skeys, gboxes, gvalid);
  matrix_kernel<<<dim3(16, NIMG), 256, 0, stream>>>(gboxes, M);
  resolve_kernel<<<NIMG, 64, 0, stream>>>(gboxes, gvalid, skeys, M, out);
}